// Round 1
// baseline (453.019 us; speedup 1.0000x reference)
//
#include <hip/hip_runtime.h>
#include <cstdint>
#include <cstddef>

// ---------------- problem constants (fixed by setup_inputs) ----------------
static constexpr int D_IN = 784;
static constexpr int H1   = 2048;
static constexpr int H2   = 10;
static constexpr int KK   = 10;
static constexpr int UU   = 2832;   // D_IN + H1
static constexpr int LL   = 128;
static constexpr int BB   = 1024;
static constexpr int TT   = 20;
static constexpr int HALF = BB * D_IN / 2;   // 401408 = 512*784
static constexpr int NCH  = 25;              // K chunks of 32 (784 -> 800 padded)
static constexpr int NLIMB = 3;              // signed base-256 limbs of round(W1*2^24)
static constexpr int XA_T  = 32 * NCH * 64;  // v4i per time-step of spike fragments
static constexpr int BITS_T = BB * 64;       // uint32 per time-step of h1s bitmask

typedef int v4i  __attribute__((ext_vector_type(4)));
typedef int v16i __attribute__((ext_vector_type(16)));

#define MFMA_I8 __builtin_amdgcn_mfma_i32_32x32x32_i8

// ---------------- JAX threefry2x32 (20 rounds), bit-exact ----------------
__device__ __forceinline__ uint32_t rotl32(uint32_t x, int d) {
  return (x << d) | (x >> (32 - d));
}
__device__ __forceinline__ void threefry2x32(uint32_t k0, uint32_t k1,
                                             uint32_t& x0, uint32_t& x1) {
  uint32_t ks2 = k0 ^ k1 ^ 0x1BD11BDAu;
  x0 += k0; x1 += k1;
#define TF_R(r) { x0 += x1; x1 = rotl32(x1, (r)); x1 ^= x0; }
  TF_R(13) TF_R(15) TF_R(26) TF_R(6)
  x0 += k1;  x1 += ks2 + 1u;
  TF_R(17) TF_R(29) TF_R(16) TF_R(24)
  x0 += ks2; x1 += k0 + 2u;
  TF_R(13) TF_R(15) TF_R(26) TF_R(6)
  x0 += k0;  x1 += k1 + 3u;
  TF_R(17) TF_R(29) TF_R(16) TF_R(24)
  x0 += k1;  x1 += ks2 + 4u;
  TF_R(13) TF_R(15) TF_R(26) TF_R(6)
  x0 += ks2; x1 += k0 + 5u;
#undef TF_R
}
__device__ __forceinline__ float bits_to_unif(uint32_t b) {
  uint32_t fb = (b >> 9) | 0x3F800000u;
  return __uint_as_float(fb) - 1.0f;
}

// ---------------- block-wide 3-way fp64 reduction + atomic ----------------
__device__ __forceinline__ double wave_red(double v) {
  #pragma unroll
  for (int off = 32; off > 0; off >>= 1) v += __shfl_down(v, off, 64);
  return v;
}
__device__ __forceinline__ void block_reduce3(double s0, double s1, double s2,
                                              double* gacc) {
  __shared__ double lds[3][4];
  int lane = threadIdx.x & 63, w = threadIdx.x >> 6;
  s0 = wave_red(s0); s1 = wave_red(s1); s2 = wave_red(s2);
  if (lane == 0) { lds[0][w] = s0; lds[1][w] = s1; lds[2][w] = s2; }
  __syncthreads();
  if (threadIdx.x == 0) {
    double t0 = 0, t1 = 0, t2 = 0;
    #pragma unroll
    for (int i = 0; i < 4; i++) { t0 += lds[0][i]; t1 += lds[1][i]; t2 += lds[2][i]; }
    atomicAdd(&gacc[0], t0); atomicAdd(&gacc[1], t1); atomicAdd(&gacc[2], t2);
  }
}

// ---------------- precompute val1/val2 (one wave per (k,u), ballot) ----------------
__global__ __launch_bounds__(256)
void precompute_vals(const float* __restrict__ vec, const int* __restrict__ cnt,
                     float* __restrict__ v1, float* __restrict__ v2) {
  int gw = (blockIdx.x * 256 + threadIdx.x) >> 6;
  int lane = threadIdx.x & 63;
  if (gw >= KK * UU) return;
  const float* p = vec + (size_t)gw * LL;
  float a = p[lane];
  float b = p[lane + 64];
  unsigned long long mlo = __ballot(a != 0.0f);
  unsigned long long mhi = __ballot(b != 0.0f);
  if (lane == 0) {
    int u = gw % UU;
    int c = cnt[gw];
    int last = mhi ? (127 - __builtin_clzll(mhi))
                   : (mlo ? (63 - __builtin_clzll(mlo)) : -1);
    if (c > 0) {
      if (last >= 0) atomicAdd(&v1[u], (float)(last - 1));
      atomicAdd(&v2[u], (float)c);
    }
  }
}

// ---------------- W2 transpose: W2T[i][j] = W2[j][i] ----------------
__global__ void make_w2t(const float* __restrict__ W2, float* __restrict__ W2T) {
  int i = blockIdx.x * 256 + threadIdx.x;
  if (i >= H1) return;
  #pragma unroll
  for (int j = 0; j < H2; j++) W2T[i * H2 + j] = W2[j * H1 + i];
}

// ---------------- W1 -> 3 signed base-256 int8 limbs of round(W1*2^24) ---------
// W1L entry index: ((ntile*NCH + chunk)*NLIMB + limb)*64 + lane  (16 B each)
// lane mapping: n = ntile*32 + (lane&31), k = chunk*32 + (lane>>5)*16 + j
__global__ __launch_bounds__(256)
void make_limbs(const float* __restrict__ W1, v4i* __restrict__ W1L) {
  int tid = blockIdx.x * 256 + threadIdx.x;   // 64*NCH*64 = 102400
  int lane = tid & 63;
  int tc = tid >> 6;                           // ntile*NCH + chunk
  int n = ((tc / NCH) << 5) + (lane & 31);
  int chunk = tc % NCH;
  int k0 = chunk * 32 + (lane >> 5) * 16;
  union { v4i v; signed char b[16]; } d[NLIMB];
  #pragma unroll
  for (int j = 0; j < 16; j++) {
    long long F = 0;
    int k = k0 + j;
    if (k < D_IN) {
      double w = (double)W1[(size_t)n * D_IN + k];
      F = llround(w * 0x1p24);
      if (F >  8355711LL) F =  8355711LL;     // representable range guards
      if (F < -8421504LL) F = -8421504LL;
    }
    #pragma unroll
    for (int l = 0; l < NLIMB; l++) {
      int dig = (int)((F + 128) & 255) - 128;
      d[l].b[j] = (signed char)dig;
      F = (F - dig) >> 8;
    }
  }
  #pragma unroll
  for (int l = 0; l < NLIMB; l++) W1L[(size_t)(tc * NLIMB + l) * 64 + lane] = d[l].v;
}

// ---------------- spike generation (state-independent!), A-fragment order -------
// XA_t entry index: (mtile*NCH + chunk)*64 + lane
// lane mapping: m = mtile*32 + (lane&31), k = chunk*32 + (lane>>5)*16 + j
__device__ __forceinline__ void gen_wave(int gw, int t,
    const float* __restrict__ input, v4i* __restrict__ XA_t,
    const float* __restrict__ v1, const float* __restrict__ v2,
    double& s0, double& s1, double& s2) {
  int lane = threadIdx.x & 63;
  int mtile = gw / NCH, chunk = gw - mtile * NCH;   // mtile in [0,16): m < 512
  int m = (mtile << 5) + (lane & 31);
  int k0 = chunk * 32 + (lane >> 5) * 16;
  uint32_t f0 = 0u, f1 = (uint32_t)t;
  threefry2x32(0u, 42u, f0, f1);
  union { v4i v; unsigned char b[16]; } r0, r1;
  s0 = 0; s1 = 0; s2 = 0;
  if (k0 < D_IN) {   // whole 16-group valid (784 = 24*32+16: only chunk24/half1 invalid)
    const float4* I0 = (const float4*)(input + (size_t)m * D_IN + k0);
    const float4* I1 = (const float4*)(input + (size_t)(m + 512) * D_IN + k0);
    float i0v[16], i1v[16];
    #pragma unroll
    for (int q = 0; q < 4; q++) {
      float4 a = I0[q], b4 = I1[q];
      i0v[q * 4 + 0] = a.x;  i0v[q * 4 + 1] = a.y;
      i0v[q * 4 + 2] = a.z;  i0v[q * 4 + 3] = a.w;
      i1v[q * 4 + 0] = b4.x; i1v[q * 4 + 1] = b4.y;
      i1v[q * 4 + 2] = b4.z; i1v[q * 4 + 3] = b4.w;
    }
    #pragma unroll
    for (int j = 0; j < 16; j++) {
      int k = k0 + j;
      uint32_t c0 = (uint32_t)(m * D_IN + k), c1 = c0 + (uint32_t)HALF;
      threefry2x32(f0, f1, c0, c1);
      float u0 = bits_to_unif(c0), u1 = bits_to_unif(c1);
      unsigned char x0 = (i0v[j] > u0) ? 1 : 0;
      unsigned char x1 = (i1v[j] > u1) ? 1 : 0;
      r0.b[j] = x0; r1.b[j] = x1;
      double xsum = (double)(x0 + x1);
      s0 += xsum * (double)v1[k];
      s1 += xsum * (double)v2[k];
      s2 += xsum;
    }
  } else {
    r0.v = (v4i){0, 0, 0, 0};
    r1.v = (v4i){0, 0, 0, 0};
  }
  XA_t[(size_t)(mtile * NCH + chunk) * 64 + lane] = r0.v;
  XA_t[(size_t)((mtile + 16) * NCH + chunk) * 64 + lane] = r1.v;   // partner m+512
}

// all 20 time-steps of spikes upfront (x is independent of network state)
__global__ __launch_bounds__(256)
void gen_all(const float* __restrict__ input, v4i* __restrict__ XA,
             const float* __restrict__ v1, const float* __restrict__ v2,
             double* __restrict__ gacc) {
  int t  = blockIdx.x / 100;                     // 20 t x 100 blocks
  int gw = (blockIdx.x % 100) * 4 + (threadIdx.x >> 6);
  double s0, s1, s2;
  gen_wave(gw, t, input, XA + (size_t)t * XA_T, v1, v2, s0, s1, s2);
  block_reduce3(s0, s1, s2, gacc);
}

// ---------------- h1: ALL 20 steps in one launch, membrane in registers --------
// grid (64 ntiles, 4); block = 4 waves, wave wv owns mtiles {mt0, mt0+1}.
// B panel (one ntile, 3 limbs, 76.8 KB) staged once in dynamic LDS, reused 20x.
// h1s emitted as ballot bitmask: bits[t][gm][ntile] bit c = spike at n=ntile*32+c.
__global__ __launch_bounds__(256)
void h1_all(const v4i* __restrict__ XA, const v4i* __restrict__ W1L,
            const float* __restrict__ b1, uint32_t* __restrict__ bits,
            const float* __restrict__ v1, const float* __restrict__ v2,
            double* __restrict__ gacc) {
  extern __shared__ v4i bl[];                    // NCH*NLIMB*64 = 4800 v4i = 76800 B
  int lane = threadIdx.x & 63, wv = threadIdx.x >> 6;
  int ntile = blockIdx.x;                        // [0,64)
  int mt0 = (blockIdx.y * 4 + wv) * 2;           // [0,32) in pairs
  {
    const v4i* wp = W1L + (size_t)ntile * (NCH * NLIMB * 64);
    for (int i = threadIdx.x; i < NCH * NLIMB * 64; i += 256) bl[i] = wp[i];
  }
  __syncthreads();

  int col = lane & 31;
  int gn = (ntile << 5) + col;
  double bias = (double)b1[gn];
  double v1n = (double)v1[D_IN + gn], v2n = (double)v2[D_IN + gn];
  int scnt = 0;                                  // spike count (v1n/v2n applied once at end)
  float mreg0[16], mreg1[16];                    // membrane for the wave's 2 tiles
  #pragma unroll
  for (int r = 0; r < 16; r++) { mreg0[r] = 0.0f; mreg1[r] = 0.0f; }

  #pragma unroll 1
  for (int t = 0; t < TT; t++) {
    const v4i* a0p = XA + (size_t)t * XA_T + (size_t)mt0 * (NCH * 64) + lane;
    const v4i* a1p = a0p + NCH * 64;
    v16i c00 = {}, c10 = {}, c20 = {}, c01 = {}, c11 = {}, c21 = {};
    // depth-2 A prefetch; B from LDS
    v4i A0s0 = a0p[0], A1s0 = a1p[0];
    v4i A0s1 = a0p[64], A1s1 = a1p[64];
    #pragma unroll 1
    for (int c = 0; c < NCH; c += 2) {
      v4i nA0a, nA1a, nA0b, nA1b;
      if (c + 2 < NCH) { nA0a = a0p[(c + 2) * 64]; nA1a = a1p[(c + 2) * 64]; }
      if (c + 3 < NCH) { nA0b = a0p[(c + 3) * 64]; nA1b = a1p[(c + 3) * 64]; }
      const v4i* bq = bl + c * (NLIMB * 64) + lane;
      v4i B0 = bq[0], B1 = bq[64], B2 = bq[128];
      c00 = MFMA_I8(A0s0, B0, c00, 0, 0, 0);
      c01 = MFMA_I8(A1s0, B0, c01, 0, 0, 0);
      c10 = MFMA_I8(A0s0, B1, c10, 0, 0, 0);
      c11 = MFMA_I8(A1s0, B1, c11, 0, 0, 0);
      c20 = MFMA_I8(A0s0, B2, c20, 0, 0, 0);
      c21 = MFMA_I8(A1s0, B2, c21, 0, 0, 0);
      if (c + 1 < NCH) {
        const v4i* br = bq + NLIMB * 64;
        v4i B0b = br[0], B1b = br[64], B2b = br[128];
        c00 = MFMA_I8(A0s1, B0b, c00, 0, 0, 0);
        c01 = MFMA_I8(A1s1, B0b, c01, 0, 0, 0);
        c10 = MFMA_I8(A0s1, B1b, c10, 0, 0, 0);
        c11 = MFMA_I8(A1s1, B1b, c11, 0, 0, 0);
        c20 = MFMA_I8(A0s1, B2b, c20, 0, 0, 0);
        c21 = MFMA_I8(A1s1, B2b, c21, 0, 0, 0);
      }
      A0s0 = nA0a; A1s0 = nA1a; A0s1 = nA0b; A1s1 = nA1b;
    }
    // C/D layout (32x32): col=lane&31, row=(r&3)+8*(r>>2)+4*(lane>>5)
    uint32_t* bt = bits + (size_t)t * BITS_T;
    #pragma unroll
    for (int mh = 0; mh < 2; mh++) {
      const v16i& q0 = mh ? c01 : c00;
      const v16i& q1 = mh ? c11 : c10;
      const v16i& q2 = mh ? c21 : c20;
      float* mr = mh ? mreg1 : mreg0;
      int mt = mt0 + mh;
      uint32_t* btm = bt + ((size_t)mt << 5) * 64 + ntile;
      #pragma unroll
      for (int r = 0; r < 16; r++) {
        double val = (double)q0[r] + 256.0 * (double)q1[r] + 65536.0 * (double)q2[r];
        double dot = val * 0x1p-24 + bias;
        float mp = mr[r];
        double mnew = (mp > 0.5f) ? dot : ((double)mp * 0.2 + dot);
        bool s = (mnew > 0.5);
        mr[r] = (float)mnew;
        unsigned long long bm = __ballot(s);
        int rowA = (r & 3) + 8 * (r >> 2);
        if ((lane & 31) == 0)
          btm[(size_t)(rowA + ((lane >> 5) << 2)) * 64] = (uint32_t)(bm >> (lane & 32));
        scnt += s ? 1 : 0;
      }
    }
  }
  double sc = (double)scnt;
  block_reduce3(sc * v1n, sc * v2n, sc, gacc);
}

// ---------------- h2: ALL 20 steps in one launch, W2 slices in registers -------
// block = 4 waves <-> 4 batch rows; wave wq covers n in [wq*512,(wq+1)*512) for all
// 4 rows (8 n per lane, weights register-resident); cross-wave combine via LDS;
// wave wq then advances the h2 chain for row (b0+wq) in lanes 0..9.
__global__ __launch_bounds__(256)
void h2_all(const uint32_t* __restrict__ bits, const float* __restrict__ W2T,
            const float* __restrict__ b2, const double* __restrict__ gacc,
            float* __restrict__ out) {
  int lane = threadIdx.x & 63, wq = threadIdx.x >> 6;
  int b0 = blockIdx.x * 4;
  float w[8][10];
  #pragma unroll
  for (int c = 0; c < 8; c++) {
    int n = (wq << 9) + (c << 6) + lane;         // n = wq*512 + c*64 + lane
    #pragma unroll
    for (int j = 0; j < 10; j++) w[c][j] = W2T[(size_t)n * H2 + j];
  }
  float m = 0.0f, sp = 0.0f, sm = 0.0f;
  float b2v = (lane < 10) ? b2[lane] : 0.0f;
  __shared__ float part[4][4][10];               // [wq][row][j]
  #pragma unroll 1
  for (int t = 0; t < TT; t++) {
    const uint32_t* bt = bits + (size_t)t * BITS_T;
    #pragma unroll
    for (int r = 0; r < 4; r++) {
      // lane L holds mask word (wq*16 + (L&15)) of row b0+r
      uint32_t myw = bt[(size_t)(b0 + r) * 64 + (wq << 4) + (lane & 15)];
      float p[10];
      #pragma unroll
      for (int j = 0; j < 10; j++) p[j] = 0.0f;
      #pragma unroll
      for (int c = 0; c < 8; c++) {
        // word for n = wq*512+c*64+lane lives at source lane 2c+(lane>>5)
        uint32_t wd = __shfl(myw, (c << 1) + (lane >> 5), 64);
        float f = (float)((wd >> (lane & 31)) & 1u);
        #pragma unroll
        for (int j = 0; j < 10; j++) p[j] += f * w[c][j];
      }
      #pragma unroll
      for (int j = 0; j < 10; j++) {
        float v = p[j];
        #pragma unroll
        for (int off = 32; off > 0; off >>= 1) v += __shfl_xor(v, off, 64);
        p[j] = v;
      }
      if (lane == 0) {
        #pragma unroll
        for (int j = 0; j < 10; j++) part[wq][r][j] = p[j];
      }
    }
    __syncthreads();
    if (lane < 10) {
      float red = part[0][wq][lane] + part[1][wq][lane]
                + part[2][wq][lane] + part[3][wq][lane];
      m = m * 0.2f * (1.0f - sp) + red + b2v;
      sp = (m > 0.5f) ? 1.0f : 0.0f;
      sm += sp;
    }
    __syncthreads();
  }
  if (lane < 10) out[(size_t)(b0 + wq) * H2 + lane] = (float)((double)sm / (double)TT);
  if (blockIdx.x == 0 && threadIdx.x < 3)
    out[(size_t)BB * H2 + threadIdx.x] = (float)gacc[threadIdx.x];
}

// ---------------- launch ----------------
extern "C" void kernel_launch(void* const* d_in, const int* in_sizes, int n_in,
                              void* d_out, int out_size, void* d_ws, size_t ws_size,
                              hipStream_t stream) {
  (void)in_sizes; (void)n_in; (void)out_size; (void)ws_size;
  const float* input = (const float*)d_in[0];
  const float* W1    = (const float*)d_in[1];
  const float* b1    = (const float*)d_in[2];
  const float* W2    = (const float*)d_in[3];
  const float* b2    = (const float*)d_in[4];
  const float* cmv   = (const float*)d_in[5];
  const int*   cmc   = (const int*)d_in[6];

  char* base = (char*)d_ws;
  // zeroed region
  float*  v1   = (float*)(base + 0);             //     11,328 B
  float*  v2   = (float*)(base + 11328);         //     11,328 B
  double* gacc = (double*)(base + 22656);        //         64 B
  const size_t ZERO_BYTES = 22720;
  // non-zeroed region (fully written before read)
  float*  W2T  = (float*)(base + 22720);         //     81,920 B
  v4i*    W1L  = (v4i*)(base + 104640);          //  4,915,200 B
  v4i*    XA   = (v4i*)(base + 5019840);         // 16,384,000 B (all 20 t)
  uint32_t* bits = (uint32_t*)(base + 21403840); //  5,242,880 B (end 26,646,720)

  hipMemsetAsync(d_ws, 0, ZERO_BYTES, stream);

  precompute_vals<<<(KK * UU) / 4, 256, 0, stream>>>(cmv, cmc, v1, v2);
  make_w2t<<<(H1 + 255) / 256, 256, 0, stream>>>(W2, W2T);
  make_limbs<<<(64 * NCH * 64) / 256, 256, 0, stream>>>(W1, W1L);
  gen_all<<<TT * 100, 256, 0, stream>>>(input, XA, v1, v2, gacc);
  h1_all<<<dim3(64, 4), 256, NCH * NLIMB * 64 * 16, stream>>>(XA, W1L, b1, bits,
                                                              v1, v2, gacc);
  h2_all<<<BB / 4, 256, 0, stream>>>(bits, W2T, b2, gacc, (float*)d_out);
}